// Round 1
// baseline (477.602 us; speedup 1.0000x reference)
//
#include <hip/hip_runtime.h>
#include <stdint.h>

// Problem constants (B, T, V, E, U)
constexpr int NB = 1024;
constexpr int NT = 80;
constexpr int NV = 50000;
constexpr int NE = 512;
constexpr int NU = 512;

typedef __attribute__((ext_vector_type(8))) __bf16 bf16x8;
typedef __attribute__((ext_vector_type(4))) float f32x4;
typedef __attribute__((ext_vector_type(4))) uint16_t u16x4;
typedef __attribute__((ext_vector_type(4))) float float4v;
typedef __attribute__((ext_vector_type(4))) uint32_t u32x4;

__device__ __forceinline__ uint16_t f2bf(float f) {
  uint32_t u = __builtin_bit_cast(uint32_t, f);
  u += 0x7FFFu + ((u >> 16) & 1u);   // round-to-nearest-even
  return (uint16_t)(u >> 16);
}
__device__ __forceinline__ float bf2f(uint16_t h) {
  uint32_t u = ((uint32_t)h) << 16;
  return __builtin_bit_cast(float, u);
}
__device__ __forceinline__ float tanh_fast(float x) {
  float e = __expf(2.0f * x);
  return 1.0f - 2.0f / (e + 1.0f);
}

// LLC-coherent (device-scope) 16B load/store: sc0 sc1 bypass L1+L2, data
// lives at the Infinity Cache coherence point -> correct regardless of
// which XCD each block lands on.
__device__ __forceinline__ void store16_cc(uint16_t* p, u32x4 v) {
  asm volatile("global_store_dwordx4 %0, %1, off sc0 sc1" :: "v"(p), "v"(v) : "memory");
}
__device__ __forceinline__ u32x4 load16_cc(const uint16_t* p) {
  u32x4 r;
  asm volatile("global_load_dwordx4 %0, %1, off sc0 sc1" : "=v"(r) : "v"(p) : "memory");
  return r;
}

// ---------------- prep kernels (unchanged) ----------------

__global__ __launch_bounds__(256) void emb_to_bf16(const float* __restrict__ in,
                                                   uint16_t* __restrict__ out) {
  int i = blockIdx.x * 256 + threadIdx.x;           // 6,400,000 float4s
  float4v v = ((const float4v*)in)[i];
  u16x4 o;
  o.x = f2bf(v.x); o.y = f2bf(v.y); o.z = f2bf(v.z); o.w = f2bf(v.w);
  ((u16x4*)out)[i] = o;
}

// Pack a [K=512][N=512] fp32 weight into MFMA-B-fragment order:
// pack[nt][ks][lane][j] = bf16( W[ks*32 + (lane>>4)*8 + j][nt*16 + (lane&15)] )
__global__ __launch_bounds__(256) void pack_w(const float* __restrict__ w,
                                              uint16_t* __restrict__ out) {
  int idx = blockIdx.x * 256 + threadIdx.x;  // 0..32767 = 32 nt * 16 ks * 64 lanes
  int lane = idx & 63;
  int ks = (idx >> 6) & 15;
  int nt = idx >> 10;
  int n  = nt * 16 + (lane & 15);
  int k0 = ks * 32 + (lane >> 4) * 8;
  uint16_t v[8];
#pragma unroll
  for (int j = 0; j < 8; j++) v[j] = f2bf(w[(size_t)(k0 + j) * NU + n]);
  u16x4* o = (u16x4*)(out + (size_t)idx * 8);
  o[0] = (u16x4){v[0], v[1], v[2], v[3]};
  o[1] = (u16x4){v[4], v[5], v[6], v[7]};
}

// ---------------- projection GEMM (unchanged) -------
__global__ __launch_bounds__(256, 2) void proj_gemm(const int* __restrict__ tokens,
                                                    const uint16_t* __restrict__ embb,
                                                    const uint16_t* __restrict__ kpack,
                                                    const float* __restrict__ bias,
                                                    uint16_t* __restrict__ xkp) {
  int wave = threadIdx.x >> 6;
  int lane = threadIdx.x & 63;
  int ln15 = lane & 15;
  int quad = lane >> 4;
  int m0 = blockIdx.x * 64;      // 1280 blocks: 80 t x 16 b-groups
  int t = m0 >> 10;
  int b0 = m0 & 1023;

  int tok[4];
#pragma unroll
  for (int mt = 0; mt < 4; mt++)
    tok[mt] = tokens[(size_t)(b0 + mt * 16 + ln15) * NT + t];

  float bv[8];
#pragma unroll
  for (int nt = 0; nt < 8; nt++) bv[nt] = bias[wave * 128 + nt * 16 + ln15];

  f32x4 acc[4][8];
#pragma unroll
  for (int mt = 0; mt < 4; mt++)
#pragma unroll
    for (int nt = 0; nt < 8; nt++) acc[mt][nt] = (f32x4){0.f, 0.f, 0.f, 0.f};

  bf16x8 aC[4], aN[4];
#pragma unroll
  for (int mt = 0; mt < 4; mt++) {
    aC[mt] = *(const bf16x8*)(embb + (size_t)tok[mt] * NE + 0 * 32 + quad * 8);
    aN[mt] = *(const bf16x8*)(embb + (size_t)tok[mt] * NE + 1 * 32 + quad * 8);
  }

#pragma unroll 1
  for (int ks = 0; ks < 16; ks++) {
    bf16x8 aF[4];
    int ksn = (ks + 2) & 15;   // wraps harmlessly for ks=14,15
#pragma unroll
    for (int mt = 0; mt < 4; mt++)
      aF[mt] = *(const bf16x8*)(embb + (size_t)tok[mt] * NE + ksn * 32 + quad * 8);
#pragma unroll
    for (int nt = 0; nt < 8; nt++) {
      int ntg = wave * 8 + nt;
      bf16x8 bfr = *(const bf16x8*)(kpack + (((size_t)ntg * 16 + ks) * 64 + lane) * 8);
#pragma unroll
      for (int mt = 0; mt < 4; mt++)
        acc[mt][nt] = __builtin_amdgcn_mfma_f32_16x16x32_bf16(aC[mt], bfr, acc[mt][nt], 0, 0, 0);
    }
#pragma unroll
    for (int mt = 0; mt < 4; mt++) { aC[mt] = aN[mt]; aN[mt] = aF[mt]; }
  }

  // epilogue: C-fragment-order tiles, coalesced 8B/lane stores
#pragma unroll
  for (int mt = 0; mt < 4; mt++) {
    int g = (b0 >> 4) + mt;
#pragma unroll
    for (int nt = 0; nt < 8; nt++) {
      int ntg = wave * 8 + nt;
      size_t tile = ((size_t)t * 64 + g) * 32 + ntg;
      u16x4 o;
      o.x = f2bf(acc[mt][nt][0] + bv[nt]);
      o.y = f2bf(acc[mt][nt][1] + bv[nt]);
      o.z = f2bf(acc[mt][nt][2] + bv[nt]);
      o.w = f2bf(acc[mt][nt][3] + bv[nt]);
      *(u16x4*)(xkp + tile * 256 + (size_t)lane * 4) = o;
    }
  }
}

// ---------------- recurrence: restructured exchange ------------
// 256 blocks x 256 threads (1/CU). Block (g = bid&63, s = bid>>6):
// rows g*16..+15, cols s*128..+127. Changes vs previous version:
//  * LDS h-tile DOUBLE-BUFFERED (2x16KB): read buf[t&1], write buf[~t&1]
//    -> the two read/write hazard barriers are gone.
//  * PER-WAVE publish: wave w's repack region is exactly ks-subregion
//    (s*4+w) (col128>>5 == wave), so each wave repacks, lgkmcnt(0),
//    reads back its own 1KB and stores it to the LLC + sets its own flag
//    WITHOUT waiting for the other waves. Chunk = 4 wave-regions.
//  * Consumer polls a 16B 4-flag vector (one device-scope load).
//  * ONE __syncthreads per step (after staging) instead of four.
//  * h-tile LDS layout XOR-swizzled: 16B-slot = quad ^ ((row>>1)&3).
//    A-read was an 8-way bank conflict (stride 64B); now 2-way (free).
//    Swizzle applied at repack-write, A-read, FC-read; copy-out/staging
//    move physical bytes verbatim so they stay consistent.
//  * xk loads software-pipelined (prefetch t+1 during the poll phase).
__global__ __launch_bounds__(256, 1)
void rnn_rec(const uint16_t* __restrict__ xkp,
             const uint16_t* __restrict__ rpack,
             const float* __restrict__ fcw,
             const float* __restrict__ fcb,
             uint16_t* __restrict__ hx,    // [2][64][4][2048] u16 (4KB chunks)
             int* __restrict__ flags,      // [64][4] quads of 4 ints, 64B apart
             float* __restrict__ out) {
  __shared__ uint16_t hS[2 * 8192];   // two 16KB h-tiles (A-frag layout, swizzled)

  const int bid = blockIdx.x;
  const int g = bid & 63, s = bid >> 6;
  const int wave = threadIdx.x >> 6, lane = threadIdx.x & 63;
  const int ln15 = lane & 15, quad = lane >> 4;
  const int ntg0 = s * 8 + wave * 2;
  const int aswz = quad ^ ((ln15 >> 1) & 3);   // swizzled 16B-slot for A-reads

  // B-frags, loaded once (128 VGPRs; 1 wave/SIMD -> 512-reg budget)
  bf16x8 bf0[16], bf1[16];
#pragma unroll
  for (int ks = 0; ks < 16; ks++) {
    bf0[ks] = *(const bf16x8*)(rpack + (((size_t)(ntg0 + 0) * 16 + ks) * 64 + lane) * 8);
    bf1[ks] = *(const bf16x8*)(rpack + (((size_t)(ntg0 + 1) * 16 + ks) * 64 + lane) * 8);
  }

  // h(0) = 0: zero both buffers (layout-independent)
  {
    u32x4 z = (u32x4){0u, 0u, 0u, 0u};
#pragma unroll
    for (int i = 0; i < 8; i++) ((u32x4*)hS)[i * 256 + threadIdx.x] = z;
  }
  __syncthreads();

  const int regionOwn = s * 4 + wave;              // own ks-subregion index
  int* flagOwn = flags + (g * 4 + s) * 16 + wave;  // flag quads 64B apart

  // prefetch xk for t=0
  u16x4 xc0 = *(const u16x4*)(xkp + (((size_t)0 * 64 + g) * 32 + ntg0 + 0) * 256 + (size_t)lane * 4);
  u16x4 xc1 = *(const u16x4*)(xkp + (((size_t)0 * 64 + g) * 32 + ntg0 + 1) * 256 + (size_t)lane * 4);

  for (int t = 0; t < NT; t++) {
    const int cur = t & 1;
    const uint16_t* hR = hS + cur * 8192;
    uint16_t* hW = hS + (cur ^ 1) * 8192;

    // compute: A from LDS buf[cur] (swizzled), B from registers
    f32x4 acc0 = (f32x4){0.f, 0.f, 0.f, 0.f};
    f32x4 acc1 = (f32x4){0.f, 0.f, 0.f, 0.f};
#pragma unroll
    for (int ks = 0; ks < 16; ks++) {
      bf16x8 a = *(const bf16x8*)(hR + (size_t)ks * 512 + ln15 * 32 + aswz * 8);
      acc0 = __builtin_amdgcn_mfma_f32_16x16x32_bf16(a, bf0[ks], acc0, 0, 0, 0);
      acc1 = __builtin_amdgcn_mfma_f32_16x16x32_bf16(a, bf1[ks], acc1, 0, 0, 0);
    }

    // tanh
    uint16_t hv0[4], hv1[4];
#pragma unroll
    for (int r = 0; r < 4; r++) {
      hv0[r] = f2bf(tanh_fast(acc0[r] + bf2f(xc0[r])));
      hv1[r] = f2bf(tanh_fast(acc1[r] + bf2f(xc1[r])));
    }

    // repack own 32 cols into hW own region (wave-local!), swizzled scatter.
    // col128 = (wave*2+i)*16 + ln15  ->  col128>>5 == wave for i in {0,1}.
#pragma unroll
    for (int i = 0; i < 2; i++) {
      const uint16_t* hv = (i == 0) ? hv0 : hv1;
      int col128 = (wave * 2 + i) * 16 + ln15;
      int qw = (col128 >> 3) & 3, j = col128 & 7;
#pragma unroll
      for (int r = 0; r < 4; r++) {
        int row = quad * 4 + r;
        hW[(size_t)regionOwn * 512 + row * 32 + (qw ^ ((row >> 1) & 3)) * 8 + j] = hv[r];
      }
    }
    asm volatile("s_waitcnt lgkmcnt(0)" ::: "memory");  // own ds_writes done (same wave)

    // publish own 1KB sub-chunk immediately: no barrier, per-wave flag
    {
      u32x4 d = *(const u32x4*)(hW + (size_t)regionOwn * 512 + (size_t)lane * 8);
      uint16_t* dst = hx + ((size_t)((t + 1) & 1) * 256 + g * 4 + s) * 2048 +
                      (size_t)wave * 512 + (size_t)lane * 8;
      store16_cc(dst, d);
      asm volatile("s_waitcnt vmcnt(0)" ::: "memory");
      if (lane == 0)
        __hip_atomic_store(flagOwn, t + 1, __ATOMIC_RELAXED, __HIP_MEMORY_SCOPE_AGENT);
    }

    // prefetch next xk (overlaps the poll/stage phase)
    {
      int tn = (t + 1 < NT) ? (t + 1) : t;
      xc0 = *(const u16x4*)(xkp + (((size_t)tn * 64 + g) * 32 + ntg0 + 0) * 256 + (size_t)lane * 4);
      xc1 = *(const u16x4*)(xkp + (((size_t)tn * 64 + g) * 32 + ntg0 + 1) * 256 + (size_t)lane * 4);
    }

    // staging: wave w in {1,2,3} fetches chunk of slice sp = (s+w)&3.
    // Last step: only s==0 blocks (which run the FC) still need partners.
    if (wave > 0 && (t < NT - 1 || s == 0)) {
      int sp = (s + wave) & 3;
      const int* fp = flags + (g * 4 + sp) * 16;
      int spin = 0;
      for (;;) {
        u32x4 f = load16_cc((const uint16_t*)fp);
        asm volatile("s_waitcnt vmcnt(0)" ::: "memory");
        if ((int)f.x >= t + 1 && (int)f.y >= t + 1 &&
            (int)f.z >= t + 1 && (int)f.w >= t + 1) break;
        if (++spin >= (1 << 16)) break;
      }
      const uint16_t* src = hx + ((size_t)((t + 1) & 1) * 256 + g * 4 + sp) * 2048;
      u32x4 v0 = load16_cc(src + (size_t)(0 * 64 + lane) * 8);
      u32x4 v1 = load16_cc(src + (size_t)(1 * 64 + lane) * 8);
      u32x4 v2 = load16_cc(src + (size_t)(2 * 64 + lane) * 8);
      u32x4 v3 = load16_cc(src + (size_t)(3 * 64 + lane) * 8);
      asm volatile("s_waitcnt vmcnt(0)" ::: "memory");
      *(u32x4*)(hW + (size_t)sp * 2048 + (size_t)(0 * 64 + lane) * 8) = v0;
      *(u32x4*)(hW + (size_t)sp * 2048 + (size_t)(1 * 64 + lane) * 8) = v1;
      *(u32x4*)(hW + (size_t)sp * 2048 + (size_t)(2 * 64 + lane) * 8) = v2;
      *(u32x4*)(hW + (size_t)sp * 2048 + (size_t)(3 * 64 + lane) * 8) = v3;
    }
    __syncthreads();   // the ONE barrier per step: h(t+1) fully staged
  }

  // final FC + sigmoid: h(80) is in buf[NT&1] == buf 0; s==0 blocks write
  if (s == 0) {
    const uint16_t* hB = hS + (NT & 1) * 8192;
#pragma unroll
    for (int rr = 0; rr < 4; rr++) {
      int row = wave * 4 + rr;
      // cols lane*8..+7: ks = lane>>2, logical qw = lane&3 -> swizzled slot
      int slot = (lane & 3) ^ ((row >> 1) & 3);
      const uint16_t* hr = hB + (size_t)(lane >> 2) * 512 + row * 32 + slot * 8;
      float p = 0.f;
#pragma unroll
      for (int j = 0; j < 8; j++) p += bf2f(hr[j]) * fcw[lane * 8 + j];
#pragma unroll
      for (int off = 32; off; off >>= 1) p += __shfl_down(p, off);
      if (lane == 0) {
        float logit = p + fcb[0];
        out[g * 16 + row] = 1.0f / (1.0f + __expf(-logit));
      }
    }
  }
}

// ---------------- launcher ----------------
extern "C" void kernel_launch(void* const* d_in, const int* in_sizes, int n_in,
                              void* d_out, int out_size, void* d_ws, size_t ws_size,
                              hipStream_t stream) {
  const int* tokens   = (const int*)d_in[0];
  const float* emb    = (const float*)d_in[1];
  const float* kernel_w = (const float*)d_in[2];
  const float* rec_w  = (const float*)d_in[3];
  const float* bias   = (const float*)d_in[4];
  const float* fcw    = (const float*)d_in[5];
  const float* fcb    = (const float*)d_in[6];
  float* out = (float*)d_out;

  // workspace: emb_bf16 51.2MB | kpack 0.5MB | rpack 0.5MB | xkp 83.9MB |
  //            hx 2MB | flags 16KB   (~138.1 MB)
  uint16_t* embb  = (uint16_t*)d_ws;
  uint16_t* kpack = embb + (size_t)NV * NE;
  uint16_t* rpack = kpack + (size_t)NE * NU;
  uint16_t* xkp   = rpack + (size_t)NU * NU;
  uint16_t* hx    = xkp + (size_t)NT * NB * NU;            // 1,048,576 u16
  int* flags      = (int*)(hx + (size_t)2 * 256 * 2048);
  // flags poisoned 0xAA -> 0xAAAAAAAA < 1 as signed int: valid initial state
  // (harness re-poisons the workspace between iterations, so the monotonic
  // flag counters restart correctly each run).

  hipLaunchKernelGGL(emb_to_bf16, dim3(25000), dim3(256), 0, stream, emb, embb);
  hipLaunchKernelGGL(pack_w, dim3(128), dim3(256), 0, stream, kernel_w, kpack);
  hipLaunchKernelGGL(pack_w, dim3(128), dim3(256), 0, stream, rec_w, rpack);
  hipLaunchKernelGGL(proj_gemm, dim3(1280), dim3(256), 0, stream, tokens, embb, kpack, bias, xkp);
  hipLaunchKernelGGL(rnn_rec, dim3(256), dim3(256), 0, stream, xkp, rpack, fcw, fcb, hx, flags, out);
}